// Round 5
// baseline (370.877 us; speedup 1.0000x reference)
//
#include <hip/hip_runtime.h>
#include <hip/hip_bf16.h>

#define NROWS 65536
#define DIM   256
#define NCLS  1000
#define CPAD  1024

typedef __attribute__((ext_vector_type(8))) short bf16x8;   // 8 bf16 = 4 VGPR
typedef __attribute__((ext_vector_type(4))) float f32x4;    // MFMA C/D

// RTNE float -> bf16 bit pattern (finite inputs only)
__device__ inline unsigned short f2bf(float x) {
    unsigned int u = __builtin_bit_cast(unsigned int, x);
    unsigned int lsb = (u >> 16) & 1u;
    u += 0x7fffu + lsb;
    return (unsigned short)(u >> 16);
}

__device__ inline float bf2f(unsigned short u) {
    unsigned int v = ((unsigned int)u) << 16;
    return __builtin_bit_cast(float, v);
}

// async global->LDS, 16 B per lane, dst = wave-uniform base + lane*16
__device__ inline void gload_lds16(const void* g, void* l) {
    __builtin_amdgcn_global_load_lds(
        (const __attribute__((address_space(1))) unsigned int*)g,
        (__attribute__((address_space(3))) unsigned int*)l, 16, 0, 0);
}

// K1: one wave per row: L2-normalize (clamp 1e-12), store bf16 e,
// label histogram via global uint atomic (65K lane-ops).
__global__ __launch_bounds__(256) void k_norm_acc(
    const float* __restrict__ emb, const int* __restrict__ labels,
    unsigned short* __restrict__ e, unsigned int* __restrict__ counts)
{
    int gid  = blockIdx.x * 256 + threadIdx.x;
    int row  = gid >> 6;
    int lane = gid & 63;
    float4 v = ((const float4*)(emb + (size_t)row * DIM))[lane];
    float ss = v.x*v.x + v.y*v.y + v.z*v.z + v.w*v.w;
    #pragma unroll
    for (int off = 1; off < 64; off <<= 1) ss += __shfl_xor(ss, off);
    float inv = 1.0f / fmaxf(sqrtf(ss), 1e-12f);
    v.x *= inv; v.y *= inv; v.z *= inv; v.w *= inv;
    ushort4 u;
    u.x = f2bf(v.x); u.y = f2bf(v.y); u.z = f2bf(v.z); u.w = f2bf(v.w);
    ((ushort4*)(e + (size_t)row * DIM))[lane] = u;
    if (lane == 0) atomicAdd(counts + labels[row], 1u);
}

// K2: exclusive prefix scan of counts -> offs, cursor. One block, 1024 thr.
__global__ __launch_bounds__(1024) void k_prefix(
    const unsigned int* __restrict__ counts, unsigned int* __restrict__ offs,
    unsigned int* __restrict__ cursor)
{
    __shared__ unsigned int s[1024];
    int t = threadIdx.x;
    s[t] = (t < NCLS) ? counts[t] : 0u;
    __syncthreads();
    for (int d = 1; d < 1024; d <<= 1) {
        unsigned int v = (t >= d) ? s[t - d] : 0u;
        __syncthreads();
        s[t] += v;
        __syncthreads();
    }
    if (t < NCLS) {
        unsigned int excl = (t == 0) ? 0u : s[t - 1];
        offs[t]   = excl;
        cursor[t] = excl;
    }
}

// K3: scatter row indices into label-sorted order.
__global__ __launch_bounds__(256) void k_scatter(
    const int* __restrict__ labels, unsigned int* __restrict__ cursor,
    int* __restrict__ sidx)
{
    int r = blockIdx.x * 256 + threadIdx.x;
    unsigned int pos = atomicAdd(&cursor[labels[r]], 1u);
    sidx[pos] = r;
}

// K4: atomic-free class sums, wave-per-row. One block per class, 4 waves;
// each row load = 64 lanes x 8 B = 512 B fully contiguous.
__global__ __launch_bounds__(256) void k_gather_sum(
    const unsigned short* __restrict__ e, const int* __restrict__ sidx,
    const unsigned int* __restrict__ offs, const unsigned int* __restrict__ counts,
    float* __restrict__ sums)
{
    __shared__ int   sidx_s[256];
    __shared__ float part[4][256];
    const int tid  = threadIdx.x;
    const int wave = tid >> 6, lane = tid & 63;
    const int c    = blockIdx.x;
    unsigned int beg = offs[c], cnt = counts[c];

    float a0 = 0.f, a1 = 0.f, a2 = 0.f, a3 = 0.f;
    for (unsigned int base = 0; base < cnt; base += 256) {
        int m = (int)(cnt - base > 256u ? 256u : cnt - base);
        __syncthreads();
        if (tid < m) sidx_s[tid] = sidx[beg + base + tid];
        __syncthreads();
        for (int u = wave; u < m; u += 4) {
            ushort4 v = ((const ushort4*)(e + (size_t)sidx_s[u] * DIM))[lane];
            a0 += bf2f(v.x); a1 += bf2f(v.y); a2 += bf2f(v.z); a3 += bf2f(v.w);
        }
    }
    ((float4*)part[wave])[lane] = make_float4(a0, a1, a2, a3);
    __syncthreads();
    sums[(size_t)c * DIM + tid] =
        part[0][tid] + part[1][tid] + part[2][tid] + part[3][tid];
}

// K5: one wave per class (padded to 1024): center = sum/max(cnt,1);
// fold 1/max(||center||,1e-8) into it; store bf16. Padded rows -> 0.
__global__ __launch_bounds__(256) void k_centers(
    const float* __restrict__ sums, const unsigned int* __restrict__ counts,
    unsigned short* __restrict__ cs)
{
    int gid  = blockIdx.x * 256 + threadIdx.x;
    int c    = gid >> 6;          // wave-uniform
    int lane = gid & 63;
    float4 v = make_float4(0.f, 0.f, 0.f, 0.f);
    if (c < NCLS) {
        v = ((const float4*)(sums + (size_t)c * DIM))[lane];
        float ic = 1.0f / fmaxf((float)counts[c], 1.0f);
        v.x *= ic; v.y *= ic; v.z *= ic; v.w *= ic;
        float ss = v.x*v.x + v.y*v.y + v.z*v.z + v.w*v.w;
        #pragma unroll
        for (int off = 1; off < 64; off <<= 1) ss += __shfl_xor(ss, off);
        float sc = 1.0f / fmaxf(sqrtf(ss), 1e-8f);
        v.x *= sc; v.y *= sc; v.z *= sc; v.w *= sc;
    }
    ushort4 u;
    u.x = f2bf(v.x); u.y = f2bf(v.y); u.z = f2bf(v.z); u.w = f2bf(v.w);
    ((ushort4*)(cs + (size_t)c * DIM))[lane] = u;
}

// K6: barrier-free bf16 MFMA GEMM + fused loss.
// A (128 rows x K=256) in LDS, glds-staged ONCE (XOR swizzle), read-only after
// one preamble barrier. B streamed global->VGPR (L2-resident 512 KB), ping-pong
// prefetch one kc ahead. Zero barriers in the K/class loop.
// Loss via identity: total = sum relu(1-s)^2/999 over all c<NCLS
//                          + sum over label cells of [(s-1)^2 - relu(1-s)^2/999]
// -> one scalar per lane, no cross-lane row bookkeeping.
#define TMB 128
#define TCB 128

__global__ __launch_bounds__(256, 2) void k_loss_mfma(
    const unsigned short* __restrict__ e, const unsigned short* __restrict__ cs,
    const int* __restrict__ labels, float* __restrict__ acc)
{
    __shared__ __align__(16) unsigned short a_s[4][TMB * 64];  // 64 KB exactly

    const int tid  = threadIdx.x;
    const int row0 = blockIdx.x * TMB;
    const int wave = tid >> 6, lane = tid & 63;
    const int wm = wave >> 1, wn = wave & 1;   // 2x2 wave grid, wave tile 64x64
    const int l16 = lane & 15, q = lane >> 4;
    const int st_r = lane >> 3;                // staging row within 8-row chunk
    const int st_s = (lane & 7) ^ st_r;        // XOR-swizzled source slice

    // labels of this lane's 16 output rows (broadcast across l16)
    int labv[16];
    #pragma unroll
    for (int mi = 0; mi < 4; ++mi)
        #pragma unroll
        for (int rg = 0; rg < 4; ++rg)
            labv[mi * 4 + rg] = labels[row0 + wm*64 + mi*16 + q*4 + rg];

    // stage A once: 4 kc-chunks x 16 row-chunks of 8 rows
    #pragma unroll
    for (int kc = 0; kc < 4; ++kc)
        #pragma unroll
        for (int ch = 0; ch < 4; ++ch) {
            int chunk = wave * 4 + ch;
            int row   = chunk * 8 + st_r;
            gload_lds16(&e[(size_t)(row0 + row) * DIM + kc * 64 + st_s * 8],
                        &a_s[kc][chunk * 512]);
        }
    __syncthreads();   // the only pre-reduction barrier: drains glds, A visible

    // B fragment loader: 8 x global_load_dwordx4; lanes (l16,q) cover
    // 16 rows x 64 contiguous bytes -> 16 fully-consumed cache lines / instr.
    #define LOADB(buf, cb_, kc_)                                               \
        {                                                                      \
            _Pragma("unroll")                                                  \
            for (int ni = 0; ni < 4; ++ni)                                     \
                _Pragma("unroll")                                              \
                for (int kk = 0; kk < 2; ++kk)                                 \
                    buf[ni][kk] = *(const bf16x8*)&cs[                         \
                        (size_t)((cb_) * TCB + wn*64 + ni*16 + l16) * DIM      \
                        + (kc_) * 64 + kk * 32 + q * 8];                       \
        }

    bf16x8 b0[4][2], b1[4][2];
    LOADB(b0, 0, 0);

    float la = 0.0f;   // per-lane loss accumulator
    const float KN = 1.0f / 999.0f;

    for (int cb = 0; cb < CPAD / TCB; ++cb) {
        f32x4 accf[4][4] = {};
        #pragma unroll
        for (int kc = 0; kc < 4; ++kc) {
            int ns = cb * 4 + kc + 1;          // prefetch next kc-step
            if (kc & 1) {
                if (ns < 32) LOADB(b0, ns >> 2, ns & 3);
            } else {
                if (ns < 32) LOADB(b1, ns >> 2, ns & 3);
            }
            #pragma unroll
            for (int kk = 0; kk < 2; ++kk) {
                bf16x8 af[4];
                #pragma unroll
                for (int mi = 0; mi < 4; ++mi) {
                    int rowA = wm*64 + mi*16 + l16;
                    af[mi] = *(const bf16x8*)&a_s[kc][
                        rowA*64 + (((kk*4 + q) ^ (rowA & 7)) * 8)];
                }
                #pragma unroll
                for (int mi = 0; mi < 4; ++mi)
                    #pragma unroll
                    for (int ni = 0; ni < 4; ++ni)
                        accf[mi][ni] = __builtin_amdgcn_mfma_f32_16x16x32_bf16(
                            af[mi],
                            (kc & 1) ? b1[ni][kk] : b0[ni][kk],
                            accf[mi][ni], 0, 0, 0);
            }
        }
        // epilogue for this class tile: C/D col = l16, row = q*4 + reg
        #pragma unroll
        for (int mi = 0; mi < 4; ++mi) {
            #pragma unroll
            for (int rg = 0; rg < 4; ++rg) {
                int lab = labv[mi * 4 + rg];
                #pragma unroll
                for (int ni = 0; ni < 4; ++ni) {
                    int c   = cb * TCB + wn*64 + ni*16 + l16;
                    float s = accf[mi][ni][rg];
                    if (c < NCLS) {
                        float t = fmaxf(1.0f - s, 0.0f);
                        la += t * t * KN;
                        if (c == lab)
                            la += (s - 1.0f) * (s - 1.0f) - t * t * KN;
                    }
                }
            }
        }
    }

    // block reduction: wave shuffle -> LDS (aliased onto a_s) -> one atomic
    __syncthreads();                    // all waves done reading a_s
    float* red = (float*)&a_s[0][0];
    #pragma unroll
    for (int off = 32; off >= 1; off >>= 1) la += __shfl_xor(la, off);
    if (lane == 0) red[wave] = la;
    __syncthreads();
    if (tid == 0) atomicAdd(acc, red[0] + red[1] + red[2] + red[3]);
    #undef LOADB
}

__global__ void k_final(const float* __restrict__ acc, float* __restrict__ out)
{
    if (threadIdx.x == 0) out[0] = acc[0] * (1.0f / (float)NROWS);
}

extern "C" void kernel_launch(void* const* d_in, const int* in_sizes, int n_in,
                              void* d_out, int out_size, void* d_ws, size_t ws_size,
                              hipStream_t stream)
{
    const float* emb    = (const float*)d_in[0];
    const int*   labels = (const int*)d_in[1];
    float*       out    = (float*)d_out;
    char*        ws     = (char*)d_ws;

    const size_t OFF_SUMS = (size_t)NROWS * DIM * 2;            // e: 32 MB
    const size_t OFF_CNT  = OFF_SUMS + (size_t)NCLS * DIM * 4;  // sums: 1 MB
    const size_t OFF_ACC  = OFF_CNT + 4096;                     // counts: 4 KB
    const size_t OFF_OFFS = OFF_ACC + 16;                       // acc: 16 B
    const size_t OFF_CUR  = OFF_OFFS + 4096;                    // offs: 4 KB
    const size_t OFF_SIDX = OFF_CUR + 4096;                     // cursor: 4 KB
    const size_t OFF_CS   = OFF_SIDX + (size_t)NROWS * 4;       // sidx: 256 KB

    unsigned short* e      = (unsigned short*)ws;
    float*          sums   = (float*)(ws + OFF_SUMS);
    unsigned int*   counts = (unsigned int*)(ws + OFF_CNT);
    float*          acc    = (float*)(ws + OFF_ACC);
    unsigned int*   offs   = (unsigned int*)(ws + OFF_OFFS);
    unsigned int*   cursor = (unsigned int*)(ws + OFF_CUR);
    int*            sidx   = (int*)(ws + OFF_SIDX);
    unsigned short* cs     = (unsigned short*)(ws + OFF_CS);

    // zero counts + acc (contiguous); everything else fully overwritten
    hipMemsetAsync(ws + OFF_CNT, 0, 4096 + 16, stream);

    k_norm_acc  <<<NROWS / 4, 256, 0, stream>>>(emb, labels, e, counts);
    k_prefix    <<<1, 1024, 0, stream>>>(counts, offs, cursor);
    k_scatter   <<<NROWS / 256, 256, 0, stream>>>(labels, cursor, sidx);
    k_gather_sum<<<NCLS, 256, 0, stream>>>(e, sidx, offs, counts, sums);
    k_centers   <<<CPAD / 4, 256, 0, stream>>>(sums, counts, cs);
    k_loss_mfma <<<NROWS / TMB, 256, 0, stream>>>(e, cs, labels, acc);
    k_final     <<<1, 64, 0, stream>>>(acc, out);
}

// Round 6
// 189.299 us; speedup vs baseline: 1.9592x; 1.9592x over previous
//
#include <hip/hip_runtime.h>
#include <hip/hip_bf16.h>

#define NROWS 65536
#define DIM   256
#define NCLS  1000
#define CPAD  1024

typedef __attribute__((ext_vector_type(8))) short bf16x8;   // 8 bf16 = 4 VGPR
typedef __attribute__((ext_vector_type(4))) float f32x4;    // MFMA C/D

// RTNE float -> bf16 bit pattern (finite inputs only)
__device__ inline unsigned short f2bf(float x) {
    unsigned int u = __builtin_bit_cast(unsigned int, x);
    unsigned int lsb = (u >> 16) & 1u;
    u += 0x7fffu + lsb;
    return (unsigned short)(u >> 16);
}

__device__ inline float bf2f(unsigned short u) {
    unsigned int v = ((unsigned int)u) << 16;
    return __builtin_bit_cast(float, v);
}

// async global->LDS, 16 B per lane, dst = wave-uniform base + lane*16
__device__ inline void gload_lds16(const void* g, void* l) {
    __builtin_amdgcn_global_load_lds(
        (const __attribute__((address_space(1))) unsigned int*)g,
        (__attribute__((address_space(3))) unsigned int*)l, 16, 0, 0);
}

// K1: one wave per row: L2-normalize (clamp 1e-12), store bf16 e,
// label histogram via global uint atomic.
__global__ __launch_bounds__(256) void k_norm_acc(
    const float* __restrict__ emb, const int* __restrict__ labels,
    unsigned short* __restrict__ e, unsigned int* __restrict__ counts)
{
    int gid  = blockIdx.x * 256 + threadIdx.x;
    int row  = gid >> 6;
    int lane = gid & 63;
    float4 v = ((const float4*)(emb + (size_t)row * DIM))[lane];
    float ss = v.x*v.x + v.y*v.y + v.z*v.z + v.w*v.w;
    #pragma unroll
    for (int off = 1; off < 64; off <<= 1) ss += __shfl_xor(ss, off);
    float inv = 1.0f / fmaxf(sqrtf(ss), 1e-12f);
    v.x *= inv; v.y *= inv; v.z *= inv; v.w *= inv;
    ushort4 u;
    u.x = f2bf(v.x); u.y = f2bf(v.y); u.z = f2bf(v.z); u.w = f2bf(v.w);
    ((ushort4*)(e + (size_t)row * DIM))[lane] = u;
    if (lane == 0) atomicAdd(counts + labels[row], 1u);
}

// K2: exclusive prefix scan of counts -> offs, cursor. One block, 1024 thr.
__global__ __launch_bounds__(1024) void k_prefix(
    const unsigned int* __restrict__ counts, unsigned int* __restrict__ offs,
    unsigned int* __restrict__ cursor)
{
    __shared__ unsigned int s[1024];
    int t = threadIdx.x;
    s[t] = (t < NCLS) ? counts[t] : 0u;
    __syncthreads();
    for (int d = 1; d < 1024; d <<= 1) {
        unsigned int v = (t >= d) ? s[t - d] : 0u;
        __syncthreads();
        s[t] += v;
        __syncthreads();
    }
    if (t < NCLS) {
        unsigned int excl = (t == 0) ? 0u : s[t - 1];
        offs[t]   = excl;
        cursor[t] = excl;
    }
}

// K3: scatter row indices into label-sorted order.
__global__ __launch_bounds__(256) void k_scatter(
    const int* __restrict__ labels, unsigned int* __restrict__ cursor,
    int* __restrict__ sidx)
{
    int r = blockIdx.x * 256 + threadIdx.x;
    unsigned int pos = atomicAdd(&cursor[labels[r]], 1u);
    sidx[pos] = r;
}

// K4: atomic-free class sums, wave-per-row. One block per class, 4 waves.
__global__ __launch_bounds__(256) void k_gather_sum(
    const unsigned short* __restrict__ e, const int* __restrict__ sidx,
    const unsigned int* __restrict__ offs, const unsigned int* __restrict__ counts,
    float* __restrict__ sums)
{
    __shared__ int   sidx_s[256];
    __shared__ float part[4][256];
    const int tid  = threadIdx.x;
    const int wave = tid >> 6, lane = tid & 63;
    const int c    = blockIdx.x;
    unsigned int beg = offs[c], cnt = counts[c];

    float a0 = 0.f, a1 = 0.f, a2 = 0.f, a3 = 0.f;
    for (unsigned int base = 0; base < cnt; base += 256) {
        int m = (int)(cnt - base > 256u ? 256u : cnt - base);
        __syncthreads();
        if (tid < m) sidx_s[tid] = sidx[beg + base + tid];
        __syncthreads();
        for (int u = wave; u < m; u += 4) {
            ushort4 v = ((const ushort4*)(e + (size_t)sidx_s[u] * DIM))[lane];
            a0 += bf2f(v.x); a1 += bf2f(v.y); a2 += bf2f(v.z); a3 += bf2f(v.w);
        }
    }
    ((float4*)part[wave])[lane] = make_float4(a0, a1, a2, a3);
    __syncthreads();
    sums[(size_t)c * DIM + tid] =
        part[0][tid] + part[1][tid] + part[2][tid] + part[3][tid];
}

// K5: one wave per class (padded to 1024): center = sum/max(cnt,1);
// fold 1/max(||center||,1e-8) into it; store bf16. Padded rows -> 0.
__global__ __launch_bounds__(256) void k_centers(
    const float* __restrict__ sums, const unsigned int* __restrict__ counts,
    unsigned short* __restrict__ cs)
{
    int gid  = blockIdx.x * 256 + threadIdx.x;
    int c    = gid >> 6;          // wave-uniform
    int lane = gid & 63;
    float4 v = make_float4(0.f, 0.f, 0.f, 0.f);
    if (c < NCLS) {
        v = ((const float4*)(sums + (size_t)c * DIM))[lane];
        float ic = 1.0f / fmaxf((float)counts[c], 1.0f);
        v.x *= ic; v.y *= ic; v.z *= ic; v.w *= ic;
        float ss = v.x*v.x + v.y*v.y + v.z*v.z + v.w*v.w;
        #pragma unroll
        for (int off = 1; off < 64; off <<= 1) ss += __shfl_xor(ss, off);
        float sc = 1.0f / fmaxf(sqrtf(ss), 1e-8f);
        v.x *= sc; v.y *= sc; v.z *= sc; v.w *= sc;
    }
    ushort4 u;
    u.x = f2bf(v.x); u.y = f2bf(v.y); u.z = f2bf(v.z); u.w = f2bf(v.w);
    ((ushort4*)(cs + (size_t)c * DIM))[lane] = u;
}

// K6: bf16 MFMA GEMM-BT + fused loss.
// A kc=0..2 resident in LDS (48 KB, staged once via glds+XOR); A kc=3 in
// 32 VGPRs. B chunks (128 classes x 64 dims) glds double-buffered (2x16 KB);
// ONE barrier per step; stage(s+1) issued right after the barrier so the
// implicit vmcnt(0) drain at the NEXT barrier only covers stage(s+1), which
// has all of compute(s) to complete. LDS = exactly 80 KB -> 2 blocks/CU.
// Epilogue: s in [-1,1] => relu(1-s)=1-s; bulk 2-op pass over all 1024
// padded classes (phantoms add exactly 24/999 per row, subtracted in
// k_final); label correction via (lr & ~48)==0 predicated pass.
#define TMB 128
#define TCB 128

__global__ __launch_bounds__(256, 2) void k_loss_mfma(
    const unsigned short* __restrict__ e, const unsigned short* __restrict__ cs,
    const int* __restrict__ labels, float* __restrict__ acc)
{
    __shared__ __align__(16) unsigned short a_s[3][TMB * 64];  // 48 KB
    __shared__ __align__(16) unsigned short b_s[2][TCB * 64];  // 32 KB

    const int tid  = threadIdx.x;
    const int row0 = blockIdx.x * TMB;
    const int wave = tid >> 6, lane = tid & 63;
    const int wm = wave >> 1, wn = wave & 1;   // 2x2 wave grid, 64x64 tiles
    const int l16 = lane & 15, q = lane >> 4;
    const int st_r = lane >> 3;                // staging row within 8-row chunk
    const int st_s = (lane & 7) ^ st_r;        // XOR-swizzled source slice

    int labv[16];
    #pragma unroll
    for (int mi = 0; mi < 4; ++mi)
        #pragma unroll
        for (int rg = 0; rg < 4; ++rg)
            labv[mi * 4 + rg] = labels[row0 + wm*64 + mi*16 + q*4 + rg];

    // stage A kc=0..2 into LDS (12 glds/wave)
    #pragma unroll
    for (int kc = 0; kc < 3; ++kc)
        #pragma unroll
        for (int ch = 0; ch < 4; ++ch) {
            int chunk = wave * 4 + ch;
            int row   = chunk * 8 + st_r;
            gload_lds16(&e[(size_t)(row0 + row) * DIM + kc * 64 + st_s * 8],
                        &a_s[kc][chunk * 512]);
        }
    // A kc=3 into registers (plain loads, no swizzle)
    bf16x8 af3[4][2];
    #pragma unroll
    for (int mi = 0; mi < 4; ++mi) {
        const unsigned short* pa =
            e + (size_t)(row0 + wm*64 + mi*16 + l16) * DIM + 192 + q * 8;
        af3[mi][0] = *(const bf16x8*)pa;
        af3[mi][1] = *(const bf16x8*)(pa + 32);
    }
    // stage B step 0
    #pragma unroll
    for (int ch = 0; ch < 4; ++ch) {
        int chunk = wave * 4 + ch;
        int row   = chunk * 8 + st_r;
        gload_lds16(&cs[(size_t)row * DIM + st_s * 8], &b_s[0][chunk * 512]);
    }
    __syncthreads();   // drains all preamble glds; A + B(0) visible

    float la_bulk = 0.0f, la_corr = 0.0f;
    const float KN = 1.0f / 999.0f;
    f32x4 accf[4][4];

    for (int s = 0; s < 32; ++s) {
        const int cb = s >> 2, kc = s & 3;
        // prefetch step s+1 into the other buffer
        if (s < 31) {
            int s2 = s + 1;
            int cb2 = s2 >> 2, kc2 = s2 & 3;
            #pragma unroll
            for (int ch = 0; ch < 4; ++ch) {
                int chunk = wave * 4 + ch;
                int row   = chunk * 8 + st_r;
                gload_lds16(&cs[(size_t)(cb2 * TCB + row) * DIM + kc2 * 64 + st_s * 8],
                            &b_s[s2 & 1][chunk * 512]);
            }
        }
        if (kc == 0) {
            #pragma unroll
            for (int mi = 0; mi < 4; ++mi)
                #pragma unroll
                for (int ni = 0; ni < 4; ++ni)
                    accf[mi][ni] = (f32x4){0.f, 0.f, 0.f, 0.f};
        }
        const unsigned short* bs = b_s[s & 1];
        #pragma unroll
        for (int kk = 0; kk < 2; ++kk) {
            bf16x8 af[4], bfr[4];
            #pragma unroll
            for (int mi = 0; mi < 4; ++mi) {
                if (kc < 3) {
                    int rowA = wm*64 + mi*16 + l16;
                    af[mi] = *(const bf16x8*)&a_s[kc][
                        rowA*64 + (((kk*4 + q) ^ (rowA & 7)) * 8)];
                } else {
                    af[mi] = af3[mi][kk];
                }
            }
            #pragma unroll
            for (int ni = 0; ni < 4; ++ni) {
                int rowB = wn*64 + ni*16 + l16;
                bfr[ni] = *(const bf16x8*)&bs[rowB*64 + (((kk*4 + q) ^ (rowB & 7)) * 8)];
            }
            #pragma unroll
            for (int mi = 0; mi < 4; ++mi)
                #pragma unroll
                for (int ni = 0; ni < 4; ++ni)
                    accf[mi][ni] = __builtin_amdgcn_mfma_f32_16x16x32_bf16(
                        af[mi], bfr[ni], accf[mi][ni], 0, 0, 0);
        }
        if (kc == 3) {
            #pragma unroll
            for (int mi = 0; mi < 4; ++mi)
                #pragma unroll
                for (int rg = 0; rg < 4; ++rg) {
                    #pragma unroll
                    for (int ni = 0; ni < 4; ++ni) {
                        float t = 1.0f - accf[mi][ni][rg];
                        la_bulk += t * t;
                    }
                    int lr = labv[mi*4 + rg] - cb*128 - wn*64 - l16;
                    if ((lr & ~48) == 0) {
                        int nih = lr >> 4;
                        float sv = (nih == 0) ? accf[mi][0][rg] :
                                   (nih == 1) ? accf[mi][1][rg] :
                                   (nih == 2) ? accf[mi][2][rg] : accf[mi][3][rg];
                        float t = 1.0f - sv;
                        la_corr += t * t;
                    }
                }
        }
        __syncthreads();   // readers of b_s[s&1] done; drain covers stage(s+1)
    }

    // block reduction: shuffle -> b_s scratch -> one atomic
    float la = la_bulk * KN + la_corr * (1.0f - KN);
    #pragma unroll
    for (int off = 32; off >= 1; off >>= 1) la += __shfl_xor(la, off);
    float* red = (float*)&b_s[0][0];
    if (lane == 0) red[wave] = la;
    __syncthreads();
    if (tid == 0) atomicAdd(acc, red[0] + red[1] + red[2] + red[3]);
}

__global__ void k_final(const float* __restrict__ acc, float* __restrict__ out)
{
    if (threadIdx.x == 0)
        out[0] = acc[0] * (1.0f / (float)NROWS) - 24.0f * (1.0f / 999.0f);
}

extern "C" void kernel_launch(void* const* d_in, const int* in_sizes, int n_in,
                              void* d_out, int out_size, void* d_ws, size_t ws_size,
                              hipStream_t stream)
{
    const float* emb    = (const float*)d_in[0];
    const int*   labels = (const int*)d_in[1];
    float*       out    = (float*)d_out;
    char*        ws     = (char*)d_ws;

    const size_t OFF_SUMS = (size_t)NROWS * DIM * 2;            // e: 32 MB
    const size_t OFF_CNT  = OFF_SUMS + (size_t)NCLS * DIM * 4;  // sums: 1 MB
    const size_t OFF_ACC  = OFF_CNT + 4096;                     // counts: 4 KB
    const size_t OFF_OFFS = OFF_ACC + 16;                       // acc: 16 B
    const size_t OFF_CUR  = OFF_OFFS + 4096;                    // offs: 4 KB
    const size_t OFF_SIDX = OFF_CUR + 4096;                     // cursor: 4 KB
    const size_t OFF_CS   = OFF_SIDX + (size_t)NROWS * 4;       // sidx: 256 KB

    unsigned short* e      = (unsigned short*)ws;
    float*          sums   = (float*)(ws + OFF_SUMS);
    unsigned int*   counts = (unsigned int*)(ws + OFF_CNT);
    float*          acc    = (float*)(ws + OFF_ACC);
    unsigned int*   offs   = (unsigned int*)(ws + OFF_OFFS);
    unsigned int*   cursor = (unsigned int*)(ws + OFF_CUR);
    int*            sidx   = (int*)(ws + OFF_SIDX);
    unsigned short* cs     = (unsigned short*)(ws + OFF_CS);

    hipMemsetAsync(ws + OFF_CNT, 0, 4096 + 16, stream);

    k_norm_acc  <<<NROWS / 4, 256, 0, stream>>>(emb, labels, e, counts);
    k_prefix    <<<1, 1024, 0, stream>>>(counts, offs, cursor);
    k_scatter   <<<NROWS / 256, 256, 0, stream>>>(labels, cursor, sidx);
    k_gather_sum<<<NCLS, 256, 0, stream>>>(e, sidx, offs, counts, sums);
    k_centers   <<<CPAD / 4, 256, 0, stream>>>(sums, counts, cs);
    k_loss_mfma <<<NROWS / TMB, 256, 0, stream>>>(e, cs, labels, acc);
    k_final     <<<1, 64, 0, stream>>>(acc, out);
}